// Round 16
// baseline (4042.394 us; speedup 1.0000x reference)
//
#include <hip/hip_runtime.h>
#include <hip/hip_bf16.h>
#include <cstdint>
#include <cstddef>

// ---------------------------------------------------------------------------
// Problem constants
// ---------------------------------------------------------------------------
constexpr int V_N = 100000;   // variables
constexpr int C_N = 420000;   // clauses
constexpr int L_N = 2 * V_N;  // literals
constexpr int E_N = 3 * C_N;  // nnz edges
constexpr int NGR = 32;       // graphs
constexpr int NROUNDS = 8;
constexpr int SCAN_NB = (L_N + 255) / 256;   // 782 scan blocks

using bf16 = __hip_bfloat16;
typedef __attribute__((ext_vector_type(8))) short short8;   // 8 bf16 (4 VGPRs)
typedef __attribute__((ext_vector_type(4))) float float4v;  // 4 fp32 acc

__device__ inline float b2f(bf16 h) { return __bfloat162float(h); }
__device__ inline bf16 f2b(float f) { return __float2bfloat16(f); }
__device__ inline float sb2f(short s) { return __uint_as_float(((uint32_t)(uint16_t)s) << 16); }
__device__ inline short f2sb(float f) { bf16 h = f2b(f); return *(short*)&h; }

template<typename T> __device__ inline float loadT(const T* p);
template<> __device__ inline float loadT<float>(const float* p) { return *p; }
template<> __device__ inline float loadT<bf16>(const bf16* p) { return b2f(*p); }

// load 8 consecutive values as f32
template<typename TX> __device__ inline void load8(const TX* p, float* v);
template<> __device__ inline void load8<bf16>(const bf16* p, float* v) {
  short8 s = *(const short8*)p;
#pragma unroll
  for (int e = 0; e < 8; e++) v[e] = sb2f(s[e]);
}
template<> __device__ inline void load8<float>(const float* p, float* v) {
  float4 a = *(const float4*)p;
  float4 b = *(const float4*)(p + 4);
  v[0] = a.x; v[1] = a.y; v[2] = a.z; v[3] = a.w;
  v[4] = b.x; v[5] = b.y; v[6] = b.z; v[7] = b.w;
}

// runtime-dtype weight load: isf32 ? f32 buffer : packed bf16 buffer
__device__ inline float wload(const void* W, size_t idx, int isf32) {
  return isf32 ? ((const float*)W)[idx] : b2f(((const bf16*)W)[idx]);
}

// ---------------------------------------------------------------------------
// Threefry-2x32 (JAX-compatible, partitionable) — host+device
// ---------------------------------------------------------------------------
__host__ __device__ inline void tf2x32(uint32_t k0, uint32_t k1,
                                       uint32_t x0, uint32_t x1,
                                       uint32_t* o0, uint32_t* o1) {
  uint32_t ks2 = k0 ^ k1 ^ 0x1BD11BDAu;
  x0 += k0; x1 += k1;
#define TFR(d) do { x0 += x1; x1 = (x1 << (d)) | (x1 >> (32 - (d))); x1 ^= x0; } while (0)
  TFR(13); TFR(15); TFR(26); TFR(6);
  x0 += k1;  x1 += ks2 + 1u;
  TFR(17); TFR(29); TFR(16); TFR(24);
  x0 += ks2; x1 += k0 + 2u;
  TFR(13); TFR(15); TFR(26); TFR(6);
  x0 += k0;  x1 += k1 + 3u;
  TFR(17); TFR(29); TFR(16); TFR(24);
  x0 += k1;  x1 += ks2 + 4u;
  TFR(13); TFR(15); TFR(26); TFR(6);
  x0 += ks2; x1 += k0 + 5u;
#undef TFR
  *o0 = x0; *o1 = x1;
}

__device__ inline uint32_t part_bits(uint32_t ka, uint32_t kb, uint32_t e) {
  uint32_t h1, h2;
  tf2x32(ka, kb, 0u, e, &h1, &h2);
  return h1 ^ h2;
}

// XLA ErfInv32 polynomial (Giles)
__device__ inline float erfinv_f32(float x) {
  float w = -log1pf(-x * x);
  float p;
  if (w < 5.0f) {
    w -= 2.5f;
    p = 2.81022636e-08f;
    p = fmaf(p, w, 3.43273939e-07f);
    p = fmaf(p, w, -3.5233877e-06f);
    p = fmaf(p, w, -4.39150654e-06f);
    p = fmaf(p, w, 0.00021858087f);
    p = fmaf(p, w, -0.00125372503f);
    p = fmaf(p, w, -0.00417768164f);
    p = fmaf(p, w, 0.246640727f);
    p = fmaf(p, w, 1.50140941f);
  } else {
    w = sqrtf(w) - 3.0f;
    p = -0.000200214257f;
    p = fmaf(p, w, 0.000100950558f);
    p = fmaf(p, w, 0.00134934322f);
    p = fmaf(p, w, -0.00367342844f);
    p = fmaf(p, w, 0.00573950773f);
    p = fmaf(p, w, -0.0076224613f);
    p = fmaf(p, w, 0.00943887047f);
    p = fmaf(p, w, 1.00167406f);
    p = fmaf(p, w, 2.83297682f);
  }
  return p * x;
}

__device__ inline float normal_from_bits(uint32_t bits) {
  float u01 = __uint_as_float((bits >> 9) | 0x3f800000u) - 1.0f;  // [0,1)
  const float lo = -0.99999994f;
  float u = u01 * 2.0f + lo;
  u = fmaxf(lo, u);
  return 1.41421356f * erfinv_f32(u);
}

// ---------------------------------------------------------------------------
// Utility kernels
// ---------------------------------------------------------------------------
__global__ void fill_f32(float* p, size_t n, float v) {
  size_t i = (size_t)blockIdx.x * blockDim.x + threadIdx.x;
  size_t stride = (size_t)gridDim.x * blockDim.x;
  for (; i < n; i += stride) p[i] = v;
}
__global__ void fill_u32(uint32_t* p, size_t n, uint32_t v) {
  size_t i = (size_t)blockIdx.x * blockDim.x + threadIdx.x;
  size_t stride = (size_t)gridDim.x * blockDim.x;
  for (; i < n; i += stride) p[i] = v;
}
__global__ void fill_b16(bf16* p, size_t n, float v) {
  size_t i = (size_t)blockIdx.x * blockDim.x + threadIdx.x;
  size_t stride = (size_t)gridDim.x * blockDim.x;
  bf16 b = f2b(v);
  for (; i < n; i += stride) p[i] = b;
}

// Detect weight dtype (R8-verified). flag=1 -> f32, flag=0 -> bf16.
__global__ void detect_dtype_kernel(const uint32_t* __restrict__ w, int* __restrict__ flag) {
  if (blockIdx.x == 0 && threadIdx.x == 0) {
    int votes = 0;
    for (int i = 0; i < 16; i++) {
      uint32_t lo = w[i] & 0xFFFFu;
      uint32_t e = (lo >> 7) & 0xFFu;
      if (e >= 0x70u && e < 0x80u) votes++;
    }
    *flag = (votes >= 12) ? 0 : 1;
  }
}

// Pack W into MFMA B-fragment order (bf16).
__global__ void pack_w_kernel(const void* __restrict__ W, const int* __restrict__ flagp,
                              int realK, int Kpad, int M, int Wld, int wcol0,
                              int srow0, float sscale, bf16* __restrict__ out) {
  int idx = blockIdx.x * 256 + threadIdx.x;
  if (idx >= Kpad * M) return;
  int j = idx & 7;
  int lane = (idx >> 3) & 63;
  int t = idx >> 9;
  int MT = M / 16;
  int kt = t / MT, nt = t - kt * MT;
  int k = kt * 32 + (lane >> 4) * 8 + j;
  int n = nt * 16 + (lane & 15);
  float v = 0.0f;
  if (k < realK) {
    v = wload(W, (size_t)k * Wld + wcol0 + n, *flagp);
    if (k >= srow0) v *= sscale;
  }
  out[idx] = f2b(v);
}

__global__ void count_deg_kernel(const int* __restrict__ lit, int* __restrict__ deg) {
  int e = blockIdx.x * 256 + threadIdx.x;
  if (e < E_N) atomicAdd(&deg[lit[e]], 1);
}

__global__ void hist32_kernel(const int* __restrict__ gid, int n, int* __restrict__ out) {
  __shared__ int bins[NGR];
  int t = threadIdx.x;
  if (t < NGR) bins[t] = 0;
  __syncthreads();
  int i = blockIdx.x * 256 + t;
  if (i < n) atomicAdd(&bins[gid[i]], 1);
  __syncthreads();
  if (t < NGR && bins[t] > 0) atomicAdd(&out[t], bins[t]);
}

__global__ void weights_kernel(const int* __restrict__ deg,
                               float* __restrict__ dw, float* __restrict__ vdw) {
  int l = blockIdx.x * 256 + threadIdx.x;
  if (l < L_N) dw[l] = rsqrtf(fmaxf((float)deg[l], 1.0f));
  if (l < V_N) vdw[l] = 4.0f * rsqrtf(fmaxf((float)(deg[l] + deg[l + V_N]), 1.0f));
}

// ---- parallel 3-phase exclusive scan of L_N degrees -> offs[L_N+1] ----
__global__ void scan_partial_kernel(const int* __restrict__ deg, int* __restrict__ part) {
  __shared__ int red[256];
  int b = blockIdx.x, t = threadIdx.x;
  int i = b * 256 + t;
  red[t] = (i < L_N) ? deg[i] : 0;
  __syncthreads();
  for (int o = 128; o > 0; o >>= 1) {
    if (t < o) red[t] += red[t + o];
    __syncthreads();
  }
  if (t == 0) part[b] = red[0];
}

__global__ void scan_base_kernel(const int* __restrict__ part, int* __restrict__ base) {
  __shared__ int buf[SCAN_NB + 1];
  int t = threadIdx.x;
  for (int i = t; i < SCAN_NB; i += 256) buf[i] = part[i];
  __syncthreads();
  if (t == 0) {
    int acc = 0;
    for (int i = 0; i < SCAN_NB; i++) { int v = buf[i]; buf[i] = acc; acc += v; }
    buf[SCAN_NB] = acc;
  }
  __syncthreads();
  for (int i = t; i <= SCAN_NB; i += 256) base[i] = buf[i];
}

__global__ void scan_write_kernel(const int* __restrict__ deg, const int* __restrict__ base,
                                  int* __restrict__ offs) {
  __shared__ int s[256];
  int b = blockIdx.x, t = threadIdx.x;
  int i = b * 256 + t;
  int v = (i < L_N) ? deg[i] : 0;
  s[t] = v;
  __syncthreads();
  for (int o = 1; o < 256; o <<= 1) {
    int x = (t >= o) ? s[t - o] : 0;
    __syncthreads();
    s[t] += x;
    __syncthreads();
  }
  if (i < L_N) offs[i] = base[b] + s[t] - v;   // exclusive
  if (b == 0 && t == 0) offs[L_N] = base[SCAN_NB];
}

__global__ void csr_fill_kernel(const int* __restrict__ lit,
                                const int* __restrict__ offs, int* __restrict__ cursor,
                                int* __restrict__ csr) {
  int e = blockIdx.x * 256 + threadIdx.x;
  if (e < E_N) {
    int l = lit[e];
    int p = atomicAdd(&cursor[l], 1);
    csr[offs[l] + p] = e / 3;
  }
}

// ---------------------------------------------------------------------------
// Fused MLP kernels (MFMA). 256 thr = 4 waves; wave w owns 16 rows.
// All epilogues stage the C-layout tile in LDS, then emit 16B stores.
// ---------------------------------------------------------------------------

// vq: q = MLP([variables|Z]); SG[v]=sigmoid(-q), SG[v+V]=sigmoid(q).
__global__ __launch_bounds__(256) void vq_fused_kernel(
    const bf16* __restrict__ variables,
    const bf16* __restrict__ W0p, const void* __restrict__ b0,
    const bf16* __restrict__ W1p, const void* __restrict__ b1,
    const int* __restrict__ flagp, uint32_t ka, uint32_t kb,
    bf16* __restrict__ SG, int N) {
  __shared__ bf16 hs[64][72];
  __shared__ bf16 sg2[64][72];
  int tid = threadIdx.x;
  int wave = tid >> 6, lane = tid & 63, quad = lane >> 4, m16 = lane & 15;
  int row = blockIdx.x * 64 + wave * 16 + m16;
  int rowc = min(row, N - 1);
  int isf32 = *flagp;
  float4v acc[4];
#pragma unroll
  for (int nt = 0; nt < 4; nt++) acc[nt] = (float4v){0.f, 0.f, 0.f, 0.f};
  const short8* w0 = (const short8*)W0p;
  for (int k0 = 0; k0 < 96; k0 += 32) {
    int ks = k0 + quad * 8;
    short8 a;
    if (ks < 64) {
      a = *(const short8*)(variables + (size_t)rowc * 64 + ks);
    } else if (ks == 64) {
#pragma unroll
      for (int e = 0; e < 8; e++)
        a[e] = (e < 4)
             ? f2sb(normal_from_bits(part_bits(ka, kb, (uint32_t)(rowc * 4 + e))))
             : (short)0;
    } else {
      a = (short8){0, 0, 0, 0, 0, 0, 0, 0};
    }
#pragma unroll
    for (int nt = 0; nt < 4; nt++) {
      short8 b = w0[((k0 >> 5) * 4 + nt) * 64 + lane];
      acc[nt] = __builtin_amdgcn_mfma_f32_16x16x32_bf16(a, b, acc[nt], 0, 0, 0);
    }
  }
  int rl = wave * 16 + quad * 4;
#pragma unroll
  for (int nt = 0; nt < 4; nt++) {
    int col = nt * 16 + m16;
    float bv = wload(b0, col, isf32);
#pragma unroll
    for (int i = 0; i < 4; i++)
      hs[rl + i][col] = f2b(fmaxf(acc[nt][i] + bv, 0.0f));
  }
  __syncthreads();
  float4v acc2[4];
#pragma unroll
  for (int nt = 0; nt < 4; nt++) acc2[nt] = (float4v){0.f, 0.f, 0.f, 0.f};
  const short8* w1 = (const short8*)W1p;
  for (int k0 = 0; k0 < 64; k0 += 32) {
    short8 a = *(const short8*)&hs[wave * 16 + m16][k0 + quad * 8];
#pragma unroll
    for (int nt = 0; nt < 4; nt++) {
      short8 b = w1[((k0 >> 5) * 4 + nt) * 64 + lane];
      acc2[nt] = __builtin_amdgcn_mfma_f32_16x16x32_bf16(a, b, acc2[nt], 0, 0, 0);
    }
  }
  __syncthreads();  // hs free; stage both sigmoid tables
#pragma unroll
  for (int nt = 0; nt < 4; nt++) {
    int col = nt * 16 + m16;
    float bv = wload(b1, col, isf32);
#pragma unroll
    for (int i = 0; i < 4; i++) {
      float q = acc2[nt][i] + bv;
      hs[rl + i][col]  = f2b(1.0f / (1.0f + expf(q)));    // sigmoid(-q)
      sg2[rl + i][col] = f2b(1.0f / (1.0f + expf(-q)));   // sigmoid(q)
    }
  }
  __syncthreads();
  int rr = tid >> 2, q4 = tid & 3;
  int grow = blockIdx.x * 64 + rr;
  if (grow < N) {
    *(short8*)&SG[(size_t)grow * 64 + q4 * 16]             = *(short8*)&hs[rr][q4 * 16];
    *(short8*)&SG[(size_t)grow * 64 + q4 * 16 + 8]         = *(short8*)&hs[rr][q4 * 16 + 8];
    *(short8*)&SG[(size_t)(grow + V_N) * 64 + q4 * 16]     = *(short8*)&sg2[rr][q4 * 16];
    *(short8*)&SG[(size_t)(grow + V_N) * 64 + q4 * 16 + 8] = *(short8*)&sg2[rr][q4 * 16 + 8];
  }
}

// cm: H = relu([clauses|clb]@W0+b0); D = H@W1+b1; Dl=D[:,:64], Dn=D[:,64:].
__global__ __launch_bounds__(256) void cm_fused_kernel(
    const bf16* __restrict__ clauses, const bf16* __restrict__ clb,
    const bf16* __restrict__ W0p, const void* __restrict__ b0,
    const bf16* __restrict__ W1p, const void* __restrict__ b1,
    const int* __restrict__ flagp,
    bf16* __restrict__ Dl, bf16* __restrict__ Dn, int N) {
  __shared__ bf16 hs[64][136];
  int tid = threadIdx.x;
  int wave = tid >> 6, lane = tid & 63, quad = lane >> 4, m16 = lane & 15;
  int row = blockIdx.x * 64 + wave * 16 + m16;
  int rowc = min(row, N - 1);
  int isf32 = *flagp;
  float4v acc[8];
#pragma unroll
  for (int nt = 0; nt < 8; nt++) acc[nt] = (float4v){0.f, 0.f, 0.f, 0.f};
  const short8* w0 = (const short8*)W0p;
  for (int k0 = 0; k0 < 128; k0 += 32) {
    int ks = k0 + quad * 8;
    const bf16* src = (ks < 64) ? clauses + (size_t)rowc * 64 + ks
                                : clb + (size_t)rowc * 64 + (ks - 64);
    short8 a = *(const short8*)src;
#pragma unroll
    for (int nt = 0; nt < 8; nt++) {
      short8 b = w0[((k0 >> 5) * 8 + nt) * 64 + lane];
      acc[nt] = __builtin_amdgcn_mfma_f32_16x16x32_bf16(a, b, acc[nt], 0, 0, 0);
    }
  }
  int rl = wave * 16 + quad * 4;
#pragma unroll
  for (int nt = 0; nt < 8; nt++) {
    int col = nt * 16 + m16;
    float bv = wload(b0, col, isf32);
#pragma unroll
    for (int i = 0; i < 4; i++)
      hs[rl + i][col] = f2b(fmaxf(acc[nt][i] + bv, 0.0f));
  }
  __syncthreads();
#pragma unroll
  for (int nt = 0; nt < 8; nt++) acc[nt] = (float4v){0.f, 0.f, 0.f, 0.f};
  const short8* w1 = (const short8*)W1p;
  for (int k0 = 0; k0 < 128; k0 += 32) {
    short8 a = *(const short8*)&hs[wave * 16 + m16][k0 + quad * 8];
#pragma unroll
    for (int nt = 0; nt < 8; nt++) {
      short8 b = w1[((k0 >> 5) * 8 + nt) * 64 + lane];
      acc[nt] = __builtin_amdgcn_mfma_f32_16x16x32_bf16(a, b, acc[nt], 0, 0, 0);
    }
  }
  __syncthreads();  // hs free; stage D (128 cols)
#pragma unroll
  for (int nt = 0; nt < 8; nt++) {
    int col = nt * 16 + m16;
    float bv = wload(b1, col, isf32);
#pragma unroll
    for (int i = 0; i < 4; i++)
      hs[rl + i][col] = f2b(acc[nt][i] + bv);
  }
  __syncthreads();
  int rr = tid >> 2, q4 = tid & 3;
  int grow = blockIdx.x * 64 + rr;
  if (grow < N) {
    int c0 = q4 * 32;
    if (q4 < 2) {
      bf16* dst = Dl + (size_t)grow * 64 + c0;
#pragma unroll
      for (int ci = 0; ci < 4; ci++)
        *(short8*)(dst + ci * 8) = *(short8*)&hs[rr][c0 + ci * 8];
    } else {
      bf16* dst = Dn + (size_t)grow * 64 + (c0 - 64);
#pragma unroll
      for (int ci = 0; ci < 4; ci++)
        *(short8*)(dst + ci * 8) = *(short8*)&hs[rr][c0 + ci * 8];
    }
  }
}

// ug: 3-layer MLP [QG|variables|VLb](K=256) ->128 ->128 ->64, NV f32 out.
__global__ __launch_bounds__(256) void ug_fused_kernel(
    const bf16* __restrict__ QG, const bf16* __restrict__ variables,
    const bf16* __restrict__ VLb,
    const bf16* __restrict__ W0p, const void* __restrict__ b0,
    const bf16* __restrict__ W1p, const void* __restrict__ b1,
    const bf16* __restrict__ W2p, const void* __restrict__ b2,
    const int* __restrict__ flagp, float* __restrict__ NV, int N) {
  __shared__ bf16 h1[64][136];
  __shared__ bf16 h2[64][136];
  int tid = threadIdx.x;
  int wave = tid >> 6, lane = tid & 63, quad = lane >> 4, m16 = lane & 15;
  int row = blockIdx.x * 64 + wave * 16 + m16;
  int rowc = min(row, N - 1);
  int isf32 = *flagp;
  int rl = wave * 16 + quad * 4;
  float4v acc[8];
#pragma unroll
  for (int nt = 0; nt < 8; nt++) acc[nt] = (float4v){0.f, 0.f, 0.f, 0.f};
  const short8* w0 = (const short8*)W0p;
  for (int k0 = 0; k0 < 256; k0 += 32) {
    int ks = k0 + quad * 8;
    const bf16* src;
    if (ks < 64)       src = QG + (size_t)rowc * 64 + ks;
    else if (ks < 128) src = variables + (size_t)rowc * 64 + (ks - 64);
    else               src = VLb + (size_t)rowc * 128 + (ks - 128);
    short8 a = *(const short8*)src;
#pragma unroll
    for (int nt = 0; nt < 8; nt++) {
      short8 b = w0[((k0 >> 5) * 8 + nt) * 64 + lane];
      acc[nt] = __builtin_amdgcn_mfma_f32_16x16x32_bf16(a, b, acc[nt], 0, 0, 0);
    }
  }
#pragma unroll
  for (int nt = 0; nt < 8; nt++) {
    int col = nt * 16 + m16;
    float bv = wload(b0, col, isf32);
#pragma unroll
    for (int i = 0; i < 4; i++)
      h1[rl + i][col] = f2b(fmaxf(acc[nt][i] + bv, 0.0f));
  }
  __syncthreads();
#pragma unroll
  for (int nt = 0; nt < 8; nt++) acc[nt] = (float4v){0.f, 0.f, 0.f, 0.f};
  const short8* w1 = (const short8*)W1p;
  for (int k0 = 0; k0 < 128; k0 += 32) {
    short8 a = *(const short8*)&h1[wave * 16 + m16][k0 + quad * 8];
#pragma unroll
    for (int nt = 0; nt < 8; nt++) {
      short8 b = w1[((k0 >> 5) * 8 + nt) * 64 + lane];
      acc[nt] = __builtin_amdgcn_mfma_f32_16x16x32_bf16(a, b, acc[nt], 0, 0, 0);
    }
  }
  __syncthreads();  // h1 reads done
#pragma unroll
  for (int nt = 0; nt < 8; nt++) {
    int col = nt * 16 + m16;
    float bv = wload(b1, col, isf32);
#pragma unroll
    for (int i = 0; i < 4; i++)
      h2[rl + i][col] = f2b(fmaxf(acc[nt][i] + bv, 0.0f));
  }
  __syncthreads();
  float4v acc3[4];
#pragma unroll
  for (int nt = 0; nt < 4; nt++) acc3[nt] = (float4v){0.f, 0.f, 0.f, 0.f};
  const short8* w2 = (const short8*)W2p;
  for (int k0 = 0; k0 < 128; k0 += 32) {
    short8 a = *(const short8*)&h2[wave * 16 + m16][k0 + quad * 8];
#pragma unroll
    for (int nt = 0; nt < 4; nt++) {
      short8 b = w2[((k0 >> 5) * 4 + nt) * 64 + lane];
      acc3[nt] = __builtin_amdgcn_mfma_f32_16x16x32_bf16(a, b, acc3[nt], 0, 0, 0);
    }
  }
  // stage NV as f32 in h1's storage (64 x 68 f32 = same bytes as 64 x 136 bf16)
  float (*nvs)[68] = (float(*)[68])h1;
#pragma unroll
  for (int nt = 0; nt < 4; nt++) {
    int col = nt * 16 + m16;
    float bv = wload(b2, col, isf32);
#pragma unroll
    for (int i = 0; i < 4; i++)
      nvs[rl + i][col] = acc3[nt][i] + bv;
  }
  __syncthreads();
  int rr = tid >> 2, q4 = tid & 3;
  int grow = blockIdx.x * 64 + rr;
  if (grow < N) {
    float* dst = NV + (size_t)grow * 64 + q4 * 16;
#pragma unroll
    for (int ci = 0; ci < 4; ci++)
      *(float4*)(dst + ci * 4) = *(float4*)&nvs[rr][q4 * 16 + ci * 4];
  }
}

// ---------------------------------------------------------------------------
// Vectorized edge / node kernels: 8 lanes per row, short8 (16B) per lane.
// ---------------------------------------------------------------------------
// cl = product of 3 gathered sigmoids; no exp.
__global__ void cl_kernel(const bf16* __restrict__ SG, const int* __restrict__ lit,
                          bf16* __restrict__ cl, float* __restrict__ stats) {
  if (blockIdx.x == 0) {
    for (int i = threadIdx.x; i < 4096; i += 256) stats[i] = 0.0f;
  }
  int t = blockIdx.x * 256 + threadIdx.x;
  int c = t >> 3, j = t & 7;
  if (c >= C_N) return;
  int l0 = lit[3 * c], l1 = lit[3 * c + 1], l2 = lit[3 * c + 2];
  short8 s0 = *(const short8*)&SG[(size_t)l0 * 64 + j * 8];
  short8 s1 = *(const short8*)&SG[(size_t)l1 * 64 + j * 8];
  short8 s2 = *(const short8*)&SG[(size_t)l2 * 64 + j * 8];
  short8 r;
#pragma unroll
  for (int e = 0; e < 8; e++)
    r[e] = f2sb(sb2f(s0[e]) * sb2f(s1[e]) * sb2f(s2[e]));
  *(short8*)&cl[(size_t)c * 64 + j * 8] = r;
}

// qgrad: CSR gather of clb; sigmoids read from SG table (no exp).
__global__ void qgrad_kernel(const bf16* __restrict__ SG, const bf16* __restrict__ clb,
                             const int* __restrict__ csr, const int* __restrict__ offs,
                             const float* __restrict__ vdw, bf16* __restrict__ QG) {
  int t = blockIdx.x * 256 + threadIdx.x;
  int v = t >> 3, j = t & 7;
  if (v >= V_N) return;
  float gp[8], gn[8];
#pragma unroll
  for (int e = 0; e < 8; e++) { gp[e] = 0.0f; gn[e] = 0.0f; }
  int p0 = offs[v], p1 = offs[v + 1];
  for (int p = p0; p < p1; p++) {
    short8 x = *(const short8*)&clb[(size_t)csr[p] * 64 + j * 8];
#pragma unroll
    for (int e = 0; e < 8; e++) gp[e] += sb2f(x[e]);
  }
  p0 = offs[v + V_N]; p1 = offs[v + V_N + 1];
  for (int p = p0; p < p1; p++) {
    short8 x = *(const short8*)&clb[(size_t)csr[p] * 64 + j * 8];
#pragma unroll
    for (int e = 0; e < 8; e++) gn[e] += sb2f(x[e]);
  }
  short8 sgn = *(const short8*)&SG[(size_t)v * 64 + j * 8];          // sigmoid(-q)
  short8 sgp = *(const short8*)&SG[(size_t)(v + V_N) * 64 + j * 8];  // sigmoid(q)
  float w = vdw[v];
  short8 r;
#pragma unroll
  for (int e = 0; e < 8; e++)
    r[e] = f2sb((-sb2f(sgp[e]) * gp[e] + sb2f(sgn[e]) * gn[e]) * w);
  *(short8*)&QG[(size_t)v * 64 + j * 8] = r;
}

__global__ void vlb_gather_kernel(const bf16* __restrict__ Dl, const int* __restrict__ csr,
                                  const int* __restrict__ offs, const float* __restrict__ dw,
                                  bf16* __restrict__ VLb, float* __restrict__ stats) {
  if (blockIdx.x == 0) {
    for (int i = threadIdx.x; i < 4096; i += 256) stats[i] = 0.0f;
  }
  int t = blockIdx.x * 256 + threadIdx.x;
  int l = t >> 3, j = t & 7;
  if (l >= L_N) return;
  float s[8];
#pragma unroll
  for (int e = 0; e < 8; e++) s[e] = 0.0f;
  int p0 = offs[l], p1 = offs[l + 1];
  for (int p = p0; p < p1; p++) {
    short8 x = *(const short8*)&Dl[(size_t)csr[p] * 64 + j * 8];
#pragma unroll
    for (int e = 0; e < 8; e++) s[e] += sb2f(x[e]);
  }
  float w = dw[l];
  size_t v = (l < V_N) ? (size_t)l : (size_t)(l - V_N);
  int col = (l < V_N) ? 0 : 64;
  short8 r;
#pragma unroll
  for (int e = 0; e < 8; e++) r[e] = f2sb(s[e] * w);
  *(short8*)&VLb[v * 128 + col + j * 8] = r;
}

// ---------------------------------------------------------------------------
// PairNorm — vectorized one-pass stats + apply.
// ---------------------------------------------------------------------------
template<typename TX>
__global__ void pn_stats_kernel(const TX* __restrict__ X,
                                const int* __restrict__ gid, int n,
                                float* __restrict__ S1, float* __restrict__ S2) {
  int wave = blockIdx.x * blockDim.y + threadIdx.y;
  int nw = gridDim.x * blockDim.y;
  int chunk = (n + nw - 1) / nw;
  int i0 = wave * chunk;
  if (i0 >= n) return;
  int i1 = min(n, i0 + chunk);
  int lane = threadIdx.x;
  int sub = lane >> 3, j = lane & 7;
  float a1[8], a2[8];
#pragma unroll
  for (int e = 0; e < 8; e++) { a1[e] = 0.0f; a2[e] = 0.0f; }
  int ifirst = i0 + sub;
  if (ifirst >= i1) return;
  int g = gid[ifirst];
  for (int i = ifirst; i < i1; i += 8) {
    int gi = gid[i];
    if (gi != g) {
#pragma unroll
      for (int e = 0; e < 8; e++) {
        atomicAdd(&S1[g * 64 + j * 8 + e], a1[e]);
        atomicAdd(&S2[g * 64 + j * 8 + e], a2[e]);
        a1[e] = 0.0f; a2[e] = 0.0f;
      }
      g = gi;
    }
    float x[8];
    load8(&X[(size_t)i * 64 + j * 8], x);
#pragma unroll
    for (int e = 0; e < 8; e++) { a1[e] += x[e]; a2[e] += x[e] * x[e]; }
  }
#pragma unroll
  for (int e = 0; e < 8; e++) {
    atomicAdd(&S1[g * 64 + j * 8 + e], a1[e]);
    atomicAdd(&S2[g * 64 + j * 8 + e], a2[e]);
  }
}

template<typename TX>
__global__ void pn_apply_kernel(const TX* __restrict__ X,
                                const int* __restrict__ gid, int n,
                                const int* __restrict__ cnt, const float* __restrict__ S1,
                                const float* __restrict__ S2, bf16* __restrict__ state,
                                float post) {
  int t = blockIdx.x * 256 + threadIdx.x;
  int i = t >> 3, j = t & 7;
  if (i >= n) return;
  int g = gid[i];
  float c = fmaxf((float)cnt[g], 1.0f);
  float m[8], tv = 0.0f;
#pragma unroll
  for (int e = 0; e < 8; e++) {
    m[e] = S1[g * 64 + j * 8 + e] / c;
    tv += S2[g * 64 + j * 8 + e] / c - m[e] * m[e];
  }
#pragma unroll
  for (int o = 1; o < 8; o <<= 1) tv += __shfl_xor(tv, o);
  float var = fmaxf(tv, 0.0f) * (1.0f / 64.0f);
  float rs = rsqrtf(var + 1e-6f);
  float x[8];
  load8(&X[(size_t)i * 64 + j * 8], x);
  short8 st = *(const short8*)&state[(size_t)i * 64 + j * 8];
  short8 r;
#pragma unroll
  for (int e = 0; e < 8; e++) {
    float xn = (x[e] - m[e]) * rs;
    r[e] = f2sb((xn * 0.25f + 0.1f * sb2f(st[e])) * post);
  }
  *(short8*)&state[(size_t)i * 64 + j * 8] = r;
}

// MFMA co MLP + noise + sigmoid. 64 rows/block; col-reduce via 16-lane shfl.
__global__ __launch_bounds__(256) void co_final_kernel(
    const bf16* __restrict__ clauses, const bf16* __restrict__ W0p,
    const void* __restrict__ b0, const void* __restrict__ W1,
    const void* __restrict__ b1, const int* __restrict__ flagp,
    uint32_t ka, uint32_t kb, float* __restrict__ out) {
  int tid = threadIdx.x;
  int wave = tid >> 6, lane = tid & 63, quad = lane >> 4, m16 = lane & 15;
  int row = blockIdx.x * 64 + wave * 16 + m16;
  int rowc = min(row, C_N - 1);
  int isf32 = *flagp;
  float4v acc[4];
#pragma unroll
  for (int nt = 0; nt < 4; nt++) acc[nt] = (float4v){0.f, 0.f, 0.f, 0.f};
  const short8* w0 = (const short8*)W0p;
  for (int k0 = 0; k0 < 64; k0 += 32) {
    short8 a = *(const short8*)&clauses[(size_t)rowc * 64 + k0 + quad * 8];
#pragma unroll
    for (int nt = 0; nt < 4; nt++) {
      short8 b = w0[((k0 >> 5) * 4 + nt) * 64 + lane];
      acc[nt] = __builtin_amdgcn_mfma_f32_16x16x32_bf16(a, b, acc[nt], 0, 0, 0);
    }
  }
  float s[4] = {0.f, 0.f, 0.f, 0.f};
#pragma unroll
  for (int nt = 0; nt < 4; nt++) {
    int col = nt * 16 + m16;
    float bv = wload(b0, col, isf32);
    float w1v = wload(W1, col, isf32);
#pragma unroll
    for (int i = 0; i < 4; i++) s[i] += fmaxf(acc[nt][i] + bv, 0.0f) * w1v;
  }
#pragma unroll
  for (int o = 1; o < 16; o <<= 1) {
#pragma unroll
    for (int i = 0; i < 4; i++) s[i] += __shfl_xor(s[i], o);
  }
  if (m16 == 0) {
    int rbase = blockIdx.x * 64 + wave * 16 + quad * 4;
    float bb = wload(b1, 0, isf32);
#pragma unroll
    for (int i = 0; i < 4; i++) {
      int r = rbase + i;
      if (r < C_N) {
        float lg = s[i] + bb + normal_from_bits(part_bits(ka, kb, (uint32_t)r));
        out[r] = 1.0f / (1.0f + expf(-lg));
      }
    }
  }
}

// ---------------------------------------------------------------------------
// Launch
// ---------------------------------------------------------------------------
extern "C" void kernel_launch(void* const* d_in, const int* in_sizes, int n_in,
                              void* d_out, int out_size, void* d_ws, size_t ws_size,
                              hipStream_t stream) {
  (void)in_sizes; (void)n_in; (void)out_size;
  const int* lit_idx    = (const int*)d_in[0];
  const int* var_gid    = (const int*)d_in[2];
  const int* clause_gid = (const int*)d_in[3];
  const void* vq_W0 = d_in[4];
  const void* vq_b0 = d_in[5];
  const void* vq_W1 = d_in[6];
  const void* vq_b1 = d_in[7];
  const void* cm_W0 = d_in[8];
  const void* cm_b0 = d_in[9];
  const void* cm_W1 = d_in[10];
  const void* cm_b1 = d_in[11];
  const void* ug_W0 = d_in[12];
  const void* ug_b0 = d_in[13];
  const void* ug_W1 = d_in[14];
  const void* ug_b1 = d_in[15];
  const void* ug_W2 = d_in[16];
  const void* ug_b2 = d_in[17];
  const void* co_W0 = d_in[18];
  const void* co_b0 = d_in[19];
  const void* co_W1 = d_in[20];
  const void* co_b1 = d_in[21];
  float* out = (float*)d_out;

  // ---- workspace layout (~215 MB peak) ----
  char* ws = (char*)d_ws;
  size_t off = 0;
  auto alloc = [&](size_t bytes) -> void* {
    void* p = ws + off;
    off = (off + bytes + 255) & ~(size_t)255;
    return p;
  };
  bf16* variables = (bf16*)alloc((size_t)V_N * 64 * 2);   // persistent state
  bf16* clauses   = (bf16*)alloc((size_t)C_N * 64 * 2);   // persistent state
  // ZE (C*64*2): clb -> Dn (in-place overlay in cm_fused) -> VLb (V*128)
  char* ZE        = (char*)alloc((size_t)C_N * 64 * 2);
  // ZD (C*64*2): SG (L*64) -> Dl (C*64) -> NV f32 (V*64)
  char* ZD        = (char*)alloc((size_t)C_N * 64 * 2);
  bf16* QG        = (bf16*)alloc((size_t)V_N * 64 * 2);
  int*  izone     = (int*)alloc((size_t)(2 * L_N + 64) * 4);
  int*  offs      = (int*)alloc((size_t)(L_N + 1) * 4);
  int*  csr       = (int*)alloc((size_t)E_N * 4);
  int*  spart     = (int*)alloc((size_t)(2 * SCAN_NB + 2) * 4);
  float* deg_f    = (float*)alloc((size_t)L_N * 4);
  float* vdw      = (float*)alloc((size_t)V_N * 4);
  float* stats    = (float*)alloc((size_t)4096 * 4);
  int*   wflag    = (int*)alloc(256);
  // packed MFMA weights (bf16)
  bf16* vq_W0p = (bf16*)alloc((size_t)96 * 64 * 2);
  bf16* vq_W1p = (bf16*)alloc((size_t)64 * 64 * 2);
  bf16* cm_W0p = (bf16*)alloc((size_t)128 * 128 * 2);
  bf16* cm_W1p = (bf16*)alloc((size_t)128 * 128 * 2);
  bf16* ug_W0p = (bf16*)alloc((size_t)256 * 128 * 2);
  bf16* ug_W1p = (bf16*)alloc((size_t)128 * 128 * 2);
  bf16* ug_W2p = (bf16*)alloc((size_t)128 * 64 * 2);
  bf16* co_W0p = (bf16*)alloc((size_t)64 * 64 * 2);
  size_t need = off;

  auto nb = [](int n, int per) { return (n + per - 1) / per; };

  if (ws_size < need) {
    fill_f32<<<nb(C_N, 256), 256, 0, stream>>>(out, (size_t)C_N, 0.5f);
    return;
  }

  bf16* clb = (bf16*)ZE;                 // C x 64
  bf16* Dn  = (bf16*)ZE;                 // C x 64 (in-place overlay)
  bf16* VLb = (bf16*)ZE;                 // V x 128 (after Dn consumed)
  bf16* SG  = (bf16*)ZD;                 // L x 64 sigmoid table (vq -> cl,qgrad)
  bf16* Dl  = (bf16*)ZD;                 // C x 64 (cm -> vlb_gather)
  float* NV = (float*)ZD;                // V x 64 f32 (after Dl consumed)

  int* deg_i  = izone;
  int* cursor = izone + L_N;
  int* cntv   = izone + 2 * L_N;
  int* cntc   = cntv + 32;
  int* sbase  = spart + SCAN_NB;         // SCAN_NB+1 entries
  float* S1 = stats;              // 32 x 64
  float* S2 = stats + 2048;       // 32 x 64

  // JAX keys = split(key(42), 9), partitionable: subkey_i = threefry(key,0,i)
  uint32_t kw0[9], kw1[9];
  for (int i = 0; i < 9; i++) tf2x32(0u, 42u, 0u, (uint32_t)i, &kw0[i], &kw1[i]);

  dim3 wb(64, 4);
  const int BIG = 1 << 30;

  // ---- setup (re-done every call) ----
  detect_dtype_kernel<<<1, 64, 0, stream>>>((const uint32_t*)vq_W0, wflag);
  fill_u32<<<nb(2 * L_N + 64, 256), 256, 0, stream>>>((uint32_t*)izone, (size_t)(2 * L_N + 64), 0u);
  count_deg_kernel<<<nb(E_N, 256), 256, 0, stream>>>(lit_idx, deg_i);
  hist32_kernel<<<nb(V_N, 256), 256, 0, stream>>>(var_gid, V_N, cntv);
  hist32_kernel<<<nb(C_N, 256), 256, 0, stream>>>(clause_gid, C_N, cntc);
  weights_kernel<<<nb(L_N, 256), 256, 0, stream>>>(deg_i, deg_f, vdw);
  scan_partial_kernel<<<SCAN_NB, 256, 0, stream>>>(deg_i, spart);
  scan_base_kernel<<<1, 256, 0, stream>>>(spart, sbase);
  scan_write_kernel<<<SCAN_NB, 256, 0, stream>>>(deg_i, sbase, offs);
  csr_fill_kernel<<<nb(E_N, 256), 256, 0, stream>>>(lit_idx, offs, cursor, csr);
  fill_b16<<<2048, 256, 0, stream>>>(variables, (size_t)V_N * 64, 1.0f);
  fill_b16<<<2048, 256, 0, stream>>>(clauses, (size_t)C_N * 64, 1.0f);
  // pack weights into MFMA B-fragment order
  pack_w_kernel<<<nb(96 * 64, 256), 256, 0, stream>>>(vq_W0, wflag, 68, 96, 64, 64, 0, BIG, 1.f, vq_W0p);
  pack_w_kernel<<<nb(64 * 64, 256), 256, 0, stream>>>(vq_W1, wflag, 64, 64, 64, 64, 0, BIG, 1.f, vq_W1p);
  pack_w_kernel<<<nb(128 * 128, 256), 256, 0, stream>>>(cm_W0, wflag, 128, 128, 128, 128, 0, 64, 4.f, cm_W0p);
  pack_w_kernel<<<nb(128 * 128, 256), 256, 0, stream>>>(cm_W1, wflag, 128, 128, 128, 128, 0, BIG, 1.f, cm_W1p);
  pack_w_kernel<<<nb(256 * 128, 256), 256, 0, stream>>>(ug_W0, wflag, 256, 256, 128, 128, 0, BIG, 1.f, ug_W0p);
  pack_w_kernel<<<nb(128 * 128, 256), 256, 0, stream>>>(ug_W1, wflag, 128, 128, 128, 128, 0, BIG, 1.f, ug_W1p);
  pack_w_kernel<<<nb(128 * 64, 256), 256, 0, stream>>>(ug_W2, wflag, 128, 128, 64, 64, 0, BIG, 1.f, ug_W2p);
  pack_w_kernel<<<nb(64 * 64, 256), 256, 0, stream>>>(co_W0, wflag, 64, 64, 64, 64, 0, BIG, 1.f, co_W0p);

  // ---- rounds (10 launches each) ----
  for (int r = 0; r < NROUNDS; r++) {
    vq_fused_kernel<<<nb(V_N, 64), 256, 0, stream>>>(
        variables, vq_W0p, vq_b0, vq_W1p, vq_b1, wflag, kw0[r], kw1[r], SG, V_N);
    cl_kernel<<<nb(C_N * 8, 256), 256, 0, stream>>>(SG, lit_idx, clb, stats);
    qgrad_kernel<<<nb(V_N * 8, 256), 256, 0, stream>>>(SG, clb, csr, offs, vdw, QG);
    cm_fused_kernel<<<nb(C_N, 64), 256, 0, stream>>>(
        clauses, clb, cm_W0p, cm_b0, cm_W1p, cm_b1, wflag, Dl, Dn, C_N);
    pn_stats_kernel<bf16><<<128, wb, 0, stream>>>(Dn, clause_gid, C_N, S1, S2);
    pn_apply_kernel<bf16><<<nb(C_N * 8, 256), 256, 0, stream>>>(
        Dn, clause_gid, C_N, cntc, S1, S2, clauses, (r == NROUNDS - 1) ? 1.0f : 0.2f);
    vlb_gather_kernel<<<nb(L_N * 8, 256), 256, 0, stream>>>(Dl, csr, offs, deg_f, VLb, stats);
    ug_fused_kernel<<<nb(V_N, 64), 256, 0, stream>>>(
        QG, variables, VLb, ug_W0p, ug_b0, ug_W1p, ug_b1, ug_W2p, ug_b2,
        wflag, NV, V_N);
    pn_stats_kernel<float><<<128, wb, 0, stream>>>(NV, var_gid, V_N, S1, S2);
    pn_apply_kernel<float><<<nb(V_N * 8, 256), 256, 0, stream>>>(
        NV, var_gid, V_N, cntv, S1, S2, variables, 1.0f);
  }
  co_final_kernel<<<nb(C_N, 64), 256, 0, stream>>>(
      clauses, co_W0p, co_b0, co_W1, co_b1, wflag, kw0[8], kw1[8], out);
}

// Round 17
// 3969.201 us; speedup vs baseline: 1.0184x; 1.0184x over previous
//
#include <hip/hip_runtime.h>
#include <hip/hip_bf16.h>
#include <cstdint>
#include <cstddef>

// ---------------------------------------------------------------------------
// Problem constants
// ---------------------------------------------------------------------------
constexpr int V_N = 100000;   // variables
constexpr int C_N = 420000;   // clauses
constexpr int L_N = 2 * V_N;  // literals
constexpr int E_N = 3 * C_N;  // nnz edges
constexpr int NGR = 32;       // graphs
constexpr int NROUNDS = 8;
constexpr int SCAN_NB = (L_N + 255) / 256;   // 782 scan blocks

using bf16 = __hip_bfloat16;
typedef __attribute__((ext_vector_type(8))) short short8;   // 8 bf16 (4 VGPRs)
typedef __attribute__((ext_vector_type(4))) float float4v;  // 4 fp32 acc

__device__ inline float b2f(bf16 h) { return __bfloat162float(h); }
__device__ inline bf16 f2b(float f) { return __float2bfloat16(f); }
__device__ inline float sb2f(short s) { return __uint_as_float(((uint32_t)(uint16_t)s) << 16); }
__device__ inline short f2sb(float f) { bf16 h = f2b(f); return *(short*)&h; }

template<typename T> __device__ inline float loadT(const T* p);
template<> __device__ inline float loadT<float>(const float* p) { return *p; }
template<> __device__ inline float loadT<bf16>(const bf16* p) { return b2f(*p); }

// load 8 consecutive values as f32
template<typename TX> __device__ inline void load8(const TX* p, float* v);
template<> __device__ inline void load8<bf16>(const bf16* p, float* v) {
  short8 s = *(const short8*)p;
#pragma unroll
  for (int e = 0; e < 8; e++) v[e] = sb2f(s[e]);
}
template<> __device__ inline void load8<float>(const float* p, float* v) {
  float4 a = *(const float4*)p;
  float4 b = *(const float4*)(p + 4);
  v[0] = a.x; v[1] = a.y; v[2] = a.z; v[3] = a.w;
  v[4] = b.x; v[5] = b.y; v[6] = b.z; v[7] = b.w;
}

// runtime-dtype weight load: isf32 ? f32 buffer : packed bf16 buffer
__device__ inline float wload(const void* W, size_t idx, int isf32) {
  return isf32 ? ((const float*)W)[idx] : b2f(((const bf16*)W)[idx]);
}

// ---------------------------------------------------------------------------
// Threefry-2x32 (JAX-compatible, partitionable) — host+device
// ---------------------------------------------------------------------------
__host__ __device__ inline void tf2x32(uint32_t k0, uint32_t k1,
                                       uint32_t x0, uint32_t x1,
                                       uint32_t* o0, uint32_t* o1) {
  uint32_t ks2 = k0 ^ k1 ^ 0x1BD11BDAu;
  x0 += k0; x1 += k1;
#define TFR(d) do { x0 += x1; x1 = (x1 << (d)) | (x1 >> (32 - (d))); x1 ^= x0; } while (0)
  TFR(13); TFR(15); TFR(26); TFR(6);
  x0 += k1;  x1 += ks2 + 1u;
  TFR(17); TFR(29); TFR(16); TFR(24);
  x0 += ks2; x1 += k0 + 2u;
  TFR(13); TFR(15); TFR(26); TFR(6);
  x0 += k0;  x1 += k1 + 3u;
  TFR(17); TFR(29); TFR(16); TFR(24);
  x0 += k1;  x1 += ks2 + 4u;
  TFR(13); TFR(15); TFR(26); TFR(6);
  x0 += ks2; x1 += k0 + 5u;
#undef TFR
  *o0 = x0; *o1 = x1;
}

__device__ inline uint32_t part_bits(uint32_t ka, uint32_t kb, uint32_t e) {
  uint32_t h1, h2;
  tf2x32(ka, kb, 0u, e, &h1, &h2);
  return h1 ^ h2;
}

// XLA ErfInv32 polynomial (Giles)
__device__ inline float erfinv_f32(float x) {
  float w = -log1pf(-x * x);
  float p;
  if (w < 5.0f) {
    w -= 2.5f;
    p = 2.81022636e-08f;
    p = fmaf(p, w, 3.43273939e-07f);
    p = fmaf(p, w, -3.5233877e-06f);
    p = fmaf(p, w, -4.39150654e-06f);
    p = fmaf(p, w, 0.00021858087f);
    p = fmaf(p, w, -0.00125372503f);
    p = fmaf(p, w, -0.00417768164f);
    p = fmaf(p, w, 0.246640727f);
    p = fmaf(p, w, 1.50140941f);
  } else {
    w = sqrtf(w) - 3.0f;
    p = -0.000200214257f;
    p = fmaf(p, w, 0.000100950558f);
    p = fmaf(p, w, 0.00134934322f);
    p = fmaf(p, w, -0.00367342844f);
    p = fmaf(p, w, 0.00573950773f);
    p = fmaf(p, w, -0.0076224613f);
    p = fmaf(p, w, 0.00943887047f);
    p = fmaf(p, w, 1.00167406f);
    p = fmaf(p, w, 2.83297682f);
  }
  return p * x;
}

__device__ inline float normal_from_bits(uint32_t bits) {
  float u01 = __uint_as_float((bits >> 9) | 0x3f800000u) - 1.0f;  // [0,1)
  const float lo = -0.99999994f;
  float u = u01 * 2.0f + lo;
  u = fmaxf(lo, u);
  return 1.41421356f * erfinv_f32(u);
}

// ---------------------------------------------------------------------------
// Utility kernels
// ---------------------------------------------------------------------------
__global__ void fill_f32(float* p, size_t n, float v) {
  size_t i = (size_t)blockIdx.x * blockDim.x + threadIdx.x;
  size_t stride = (size_t)gridDim.x * blockDim.x;
  for (; i < n; i += stride) p[i] = v;
}
__global__ void fill_u32(uint32_t* p, size_t n, uint32_t v) {
  size_t i = (size_t)blockIdx.x * blockDim.x + threadIdx.x;
  size_t stride = (size_t)gridDim.x * blockDim.x;
  for (; i < n; i += stride) p[i] = v;
}
__global__ void fill_b16(bf16* p, size_t n, float v) {
  size_t i = (size_t)blockIdx.x * blockDim.x + threadIdx.x;
  size_t stride = (size_t)gridDim.x * blockDim.x;
  bf16 b = f2b(v);
  for (; i < n; i += stride) p[i] = b;
}

// Detect weight dtype (R8-verified). flag=1 -> f32, flag=0 -> bf16.
__global__ void detect_dtype_kernel(const uint32_t* __restrict__ w, int* __restrict__ flag) {
  if (blockIdx.x == 0 && threadIdx.x == 0) {
    int votes = 0;
    for (int i = 0; i < 16; i++) {
      uint32_t lo = w[i] & 0xFFFFu;
      uint32_t e = (lo >> 7) & 0xFFu;
      if (e >= 0x70u && e < 0x80u) votes++;
    }
    *flag = (votes >= 12) ? 0 : 1;
  }
}

// Pack W into MFMA B-fragment order (bf16).
__global__ void pack_w_kernel(const void* __restrict__ W, const int* __restrict__ flagp,
                              int realK, int Kpad, int M, int Wld, int wcol0,
                              int srow0, float sscale, bf16* __restrict__ out) {
  int idx = blockIdx.x * 256 + threadIdx.x;
  if (idx >= Kpad * M) return;
  int j = idx & 7;
  int lane = (idx >> 3) & 63;
  int t = idx >> 9;
  int MT = M / 16;
  int kt = t / MT, nt = t - kt * MT;
  int k = kt * 32 + (lane >> 4) * 8 + j;
  int n = nt * 16 + (lane & 15);
  float v = 0.0f;
  if (k < realK) {
    v = wload(W, (size_t)k * Wld + wcol0 + n, *flagp);
    if (k >= srow0) v *= sscale;
  }
  out[idx] = f2b(v);
}

__global__ void count_deg_kernel(const int* __restrict__ lit, int* __restrict__ deg) {
  int e = blockIdx.x * 256 + threadIdx.x;
  if (e < E_N) atomicAdd(&deg[lit[e]], 1);
}

__global__ void hist32_kernel(const int* __restrict__ gid, int n, int* __restrict__ out) {
  __shared__ int bins[NGR];
  int t = threadIdx.x;
  if (t < NGR) bins[t] = 0;
  __syncthreads();
  int i = blockIdx.x * 256 + t;
  if (i < n) atomicAdd(&bins[gid[i]], 1);
  __syncthreads();
  if (t < NGR && bins[t] > 0) atomicAdd(&out[t], bins[t]);
}

__global__ void weights_kernel(const int* __restrict__ deg,
                               float* __restrict__ dw, float* __restrict__ vdw) {
  int l = blockIdx.x * 256 + threadIdx.x;
  if (l < L_N) dw[l] = rsqrtf(fmaxf((float)deg[l], 1.0f));
  if (l < V_N) vdw[l] = 4.0f * rsqrtf(fmaxf((float)(deg[l] + deg[l + V_N]), 1.0f));
}

// ---- parallel 3-phase exclusive scan of L_N degrees -> offs[L_N+1] ----
__global__ void scan_partial_kernel(const int* __restrict__ deg, int* __restrict__ part) {
  __shared__ int red[256];
  int b = blockIdx.x, t = threadIdx.x;
  int i = b * 256 + t;
  red[t] = (i < L_N) ? deg[i] : 0;
  __syncthreads();
  for (int o = 128; o > 0; o >>= 1) {
    if (t < o) red[t] += red[t + o];
    __syncthreads();
  }
  if (t == 0) part[b] = red[0];
}

__global__ void scan_base_kernel(const int* __restrict__ part, int* __restrict__ base) {
  __shared__ int buf[SCAN_NB + 1];
  int t = threadIdx.x;
  for (int i = t; i < SCAN_NB; i += 256) buf[i] = part[i];
  __syncthreads();
  if (t == 0) {
    int acc = 0;
    for (int i = 0; i < SCAN_NB; i++) { int v = buf[i]; buf[i] = acc; acc += v; }
    buf[SCAN_NB] = acc;
  }
  __syncthreads();
  for (int i = t; i <= SCAN_NB; i += 256) base[i] = buf[i];
}

__global__ void scan_write_kernel(const int* __restrict__ deg, const int* __restrict__ base,
                                  int* __restrict__ offs) {
  __shared__ int s[256];
  int b = blockIdx.x, t = threadIdx.x;
  int i = b * 256 + t;
  int v = (i < L_N) ? deg[i] : 0;
  s[t] = v;
  __syncthreads();
  for (int o = 1; o < 256; o <<= 1) {
    int x = (t >= o) ? s[t - o] : 0;
    __syncthreads();
    s[t] += x;
    __syncthreads();
  }
  if (i < L_N) offs[i] = base[b] + s[t] - v;   // exclusive
  if (b == 0 && t == 0) offs[L_N] = base[SCAN_NB];
}

__global__ void csr_fill_kernel(const int* __restrict__ lit,
                                const int* __restrict__ offs, int* __restrict__ cursor,
                                int* __restrict__ csr) {
  int e = blockIdx.x * 256 + threadIdx.x;
  if (e < E_N) {
    int l = lit[e];
    int p = atomicAdd(&cursor[l], 1);
    csr[offs[l] + p] = e / 3;
  }
}

// ---------------------------------------------------------------------------
// Fused MLP kernels (MFMA). 256 thr = 4 waves; wave w owns 16 rows.
// (R15 epilogues: direct C-layout stores — measured equal to staged.)
// ---------------------------------------------------------------------------

// vq: q = MLP([variables|Z]); SG[v]=sigmoid(-q), SG[v+V]=sigmoid(q).
__global__ __launch_bounds__(256) void vq_fused_kernel(
    const bf16* __restrict__ variables,
    const bf16* __restrict__ W0p, const void* __restrict__ b0,
    const bf16* __restrict__ W1p, const void* __restrict__ b1,
    const int* __restrict__ flagp, uint32_t ka, uint32_t kb,
    bf16* __restrict__ SG, int N) {
  __shared__ bf16 hs[64][72];
  int tid = threadIdx.x;
  int wave = tid >> 6, lane = tid & 63, quad = lane >> 4, m16 = lane & 15;
  int row = blockIdx.x * 64 + wave * 16 + m16;
  int rowc = min(row, N - 1);
  int isf32 = *flagp;
  float4v acc[4];
#pragma unroll
  for (int nt = 0; nt < 4; nt++) acc[nt] = (float4v){0.f, 0.f, 0.f, 0.f};
  const short8* w0 = (const short8*)W0p;
  for (int k0 = 0; k0 < 96; k0 += 32) {
    int ks = k0 + quad * 8;
    short8 a;
    if (ks < 64) {
      a = *(const short8*)(variables + (size_t)rowc * 64 + ks);
    } else if (ks == 64) {
#pragma unroll
      for (int e = 0; e < 8; e++)
        a[e] = (e < 4)
             ? f2sb(normal_from_bits(part_bits(ka, kb, (uint32_t)(rowc * 4 + e))))
             : (short)0;
    } else {
      a = (short8){0, 0, 0, 0, 0, 0, 0, 0};
    }
#pragma unroll
    for (int nt = 0; nt < 4; nt++) {
      short8 b = w0[((k0 >> 5) * 4 + nt) * 64 + lane];
      acc[nt] = __builtin_amdgcn_mfma_f32_16x16x32_bf16(a, b, acc[nt], 0, 0, 0);
    }
  }
  int rl = wave * 16 + quad * 4;
#pragma unroll
  for (int nt = 0; nt < 4; nt++) {
    int col = nt * 16 + m16;
    float bv = wload(b0, col, isf32);
#pragma unroll
    for (int i = 0; i < 4; i++)
      hs[rl + i][col] = f2b(fmaxf(acc[nt][i] + bv, 0.0f));
  }
  __syncthreads();
  float4v acc2[4];
#pragma unroll
  for (int nt = 0; nt < 4; nt++) acc2[nt] = (float4v){0.f, 0.f, 0.f, 0.f};
  const short8* w1 = (const short8*)W1p;
  for (int k0 = 0; k0 < 64; k0 += 32) {
    short8 a = *(const short8*)&hs[wave * 16 + m16][k0 + quad * 8];
#pragma unroll
    for (int nt = 0; nt < 4; nt++) {
      short8 b = w1[((k0 >> 5) * 4 + nt) * 64 + lane];
      acc2[nt] = __builtin_amdgcn_mfma_f32_16x16x32_bf16(a, b, acc2[nt], 0, 0, 0);
    }
  }
  int rbase = blockIdx.x * 64 + wave * 16 + quad * 4;
#pragma unroll
  for (int nt = 0; nt < 4; nt++) {
    int col = nt * 16 + m16;
    float bv = wload(b1, col, isf32);
#pragma unroll
    for (int i = 0; i < 4; i++) {
      int r = rbase + i;
      if (r < N) {
        float q = acc2[nt][i] + bv;
        SG[(size_t)r * 64 + col] = f2b(1.0f / (1.0f + expf(q)));           // sigmoid(-q)
        SG[(size_t)(r + V_N) * 64 + col] = f2b(1.0f / (1.0f + expf(-q)));  // sigmoid(q)
      }
    }
  }
}

// cm: H = relu([clauses|clb]@W0+b0); D = H@W1+b1; Dl=D[:,:64], Dn=D[:,64:].
// Dn overlays clb in-place (block reads its own rows pre-barrier; qgrad done).
__global__ __launch_bounds__(256) void cm_fused_kernel(
    const bf16* __restrict__ clauses, const bf16* __restrict__ clb,
    const bf16* __restrict__ W0p, const void* __restrict__ b0,
    const bf16* __restrict__ W1p, const void* __restrict__ b1,
    const int* __restrict__ flagp,
    bf16* __restrict__ Dl, bf16* __restrict__ Dn, int N) {
  __shared__ bf16 hs[64][136];
  int tid = threadIdx.x;
  int wave = tid >> 6, lane = tid & 63, quad = lane >> 4, m16 = lane & 15;
  int row = blockIdx.x * 64 + wave * 16 + m16;
  int rowc = min(row, N - 1);
  int isf32 = *flagp;
  float4v acc[8];
#pragma unroll
  for (int nt = 0; nt < 8; nt++) acc[nt] = (float4v){0.f, 0.f, 0.f, 0.f};
  const short8* w0 = (const short8*)W0p;
  for (int k0 = 0; k0 < 128; k0 += 32) {
    int ks = k0 + quad * 8;
    const bf16* src = (ks < 64) ? clauses + (size_t)rowc * 64 + ks
                                : clb + (size_t)rowc * 64 + (ks - 64);
    short8 a = *(const short8*)src;
#pragma unroll
    for (int nt = 0; nt < 8; nt++) {
      short8 b = w0[((k0 >> 5) * 8 + nt) * 64 + lane];
      acc[nt] = __builtin_amdgcn_mfma_f32_16x16x32_bf16(a, b, acc[nt], 0, 0, 0);
    }
  }
  int rl = wave * 16 + quad * 4;
#pragma unroll
  for (int nt = 0; nt < 8; nt++) {
    int col = nt * 16 + m16;
    float bv = wload(b0, col, isf32);
#pragma unroll
    for (int i = 0; i < 4; i++)
      hs[rl + i][col] = f2b(fmaxf(acc[nt][i] + bv, 0.0f));
  }
  __syncthreads();
#pragma unroll
  for (int nt = 0; nt < 8; nt++) acc[nt] = (float4v){0.f, 0.f, 0.f, 0.f};
  const short8* w1 = (const short8*)W1p;
  for (int k0 = 0; k0 < 128; k0 += 32) {
    short8 a = *(const short8*)&hs[wave * 16 + m16][k0 + quad * 8];
#pragma unroll
    for (int nt = 0; nt < 8; nt++) {
      short8 b = w1[((k0 >> 5) * 8 + nt) * 64 + lane];
      acc[nt] = __builtin_amdgcn_mfma_f32_16x16x32_bf16(a, b, acc[nt], 0, 0, 0);
    }
  }
  int rbase = blockIdx.x * 64 + wave * 16 + quad * 4;
#pragma unroll
  for (int nt = 0; nt < 8; nt++) {
    int col = nt * 16 + m16;
    float bv = wload(b1, col, isf32);
#pragma unroll
    for (int i = 0; i < 4; i++) {
      int r = rbase + i;
      if (r < N) {
        float v = acc[nt][i] + bv;
        if (col < 64) Dl[(size_t)r * 64 + col] = f2b(v);
        else          Dn[(size_t)r * 64 + (col - 64)] = f2b(v);
      }
    }
  }
}

// ug: 3-layer MLP [QG|variables|VLb](K=256) ->128 ->128 ->64, NV f32 out.
__global__ __launch_bounds__(256) void ug_fused_kernel(
    const bf16* __restrict__ QG, const bf16* __restrict__ variables,
    const bf16* __restrict__ VLb,
    const bf16* __restrict__ W0p, const void* __restrict__ b0,
    const bf16* __restrict__ W1p, const void* __restrict__ b1,
    const bf16* __restrict__ W2p, const void* __restrict__ b2,
    const int* __restrict__ flagp, float* __restrict__ NV, int N) {
  __shared__ bf16 h1[64][136];
  __shared__ bf16 h2[64][136];
  int tid = threadIdx.x;
  int wave = tid >> 6, lane = tid & 63, quad = lane >> 4, m16 = lane & 15;
  int row = blockIdx.x * 64 + wave * 16 + m16;
  int rowc = min(row, N - 1);
  int isf32 = *flagp;
  int rl = wave * 16 + quad * 4;
  float4v acc[8];
#pragma unroll
  for (int nt = 0; nt < 8; nt++) acc[nt] = (float4v){0.f, 0.f, 0.f, 0.f};
  const short8* w0 = (const short8*)W0p;
  for (int k0 = 0; k0 < 256; k0 += 32) {
    int ks = k0 + quad * 8;
    const bf16* src;
    if (ks < 64)       src = QG + (size_t)rowc * 64 + ks;
    else if (ks < 128) src = variables + (size_t)rowc * 64 + (ks - 64);
    else               src = VLb + (size_t)rowc * 128 + (ks - 128);
    short8 a = *(const short8*)src;
#pragma unroll
    for (int nt = 0; nt < 8; nt++) {
      short8 b = w0[((k0 >> 5) * 8 + nt) * 64 + lane];
      acc[nt] = __builtin_amdgcn_mfma_f32_16x16x32_bf16(a, b, acc[nt], 0, 0, 0);
    }
  }
#pragma unroll
  for (int nt = 0; nt < 8; nt++) {
    int col = nt * 16 + m16;
    float bv = wload(b0, col, isf32);
#pragma unroll
    for (int i = 0; i < 4; i++)
      h1[rl + i][col] = f2b(fmaxf(acc[nt][i] + bv, 0.0f));
  }
  __syncthreads();
#pragma unroll
  for (int nt = 0; nt < 8; nt++) acc[nt] = (float4v){0.f, 0.f, 0.f, 0.f};
  const short8* w1 = (const short8*)W1p;
  for (int k0 = 0; k0 < 128; k0 += 32) {
    short8 a = *(const short8*)&h1[wave * 16 + m16][k0 + quad * 8];
#pragma unroll
    for (int nt = 0; nt < 8; nt++) {
      short8 b = w1[((k0 >> 5) * 8 + nt) * 64 + lane];
      acc[nt] = __builtin_amdgcn_mfma_f32_16x16x32_bf16(a, b, acc[nt], 0, 0, 0);
    }
  }
#pragma unroll
  for (int nt = 0; nt < 8; nt++) {
    int col = nt * 16 + m16;
    float bv = wload(b1, col, isf32);
#pragma unroll
    for (int i = 0; i < 4; i++)
      h2[rl + i][col] = f2b(fmaxf(acc[nt][i] + bv, 0.0f));
  }
  __syncthreads();
  float4v acc3[4];
#pragma unroll
  for (int nt = 0; nt < 4; nt++) acc3[nt] = (float4v){0.f, 0.f, 0.f, 0.f};
  const short8* w2 = (const short8*)W2p;
  for (int k0 = 0; k0 < 128; k0 += 32) {
    short8 a = *(const short8*)&h2[wave * 16 + m16][k0 + quad * 8];
#pragma unroll
    for (int nt = 0; nt < 4; nt++) {
      short8 b = w2[((k0 >> 5) * 4 + nt) * 64 + lane];
      acc3[nt] = __builtin_amdgcn_mfma_f32_16x16x32_bf16(a, b, acc3[nt], 0, 0, 0);
    }
  }
  int rbase = blockIdx.x * 64 + wave * 16 + quad * 4;
#pragma unroll
  for (int nt = 0; nt < 4; nt++) {
    int col = nt * 16 + m16;
    float bv = wload(b2, col, isf32);
#pragma unroll
    for (int i = 0; i < 4; i++) {
      int r = rbase + i;
      if (r < N) NV[(size_t)r * 64 + col] = acc3[nt][i] + bv;
    }
  }
}

// ---------------------------------------------------------------------------
// Vectorized edge / node device bodies (8 lanes/row, short8 per lane).
// ---------------------------------------------------------------------------
__device__ inline void cl_body(int bidx, const bf16* SG, const int* lit,
                               bf16* cl, float* statsC) {
  if (bidx == 0) {
    for (int i = threadIdx.x; i < 4096; i += 256) statsC[i] = 0.0f;
  }
  int t = bidx * 256 + threadIdx.x;
  int c = t >> 3, j = t & 7;
  if (c >= C_N) return;
  int l0 = lit[3 * c], l1 = lit[3 * c + 1], l2 = lit[3 * c + 2];
  short8 s0 = *(const short8*)&SG[(size_t)l0 * 64 + j * 8];
  short8 s1 = *(const short8*)&SG[(size_t)l1 * 64 + j * 8];
  short8 s2 = *(const short8*)&SG[(size_t)l2 * 64 + j * 8];
  short8 r;
#pragma unroll
  for (int e = 0; e < 8; e++)
    r[e] = f2sb(sb2f(s0[e]) * sb2f(s1[e]) * sb2f(s2[e]));
  *(short8*)&cl[(size_t)c * 64 + j * 8] = r;
}

__global__ void cl_kernel(const bf16* __restrict__ SG, const int* __restrict__ lit,
                          bf16* __restrict__ cl, float* __restrict__ statsC) {
  cl_body(blockIdx.x, SG, lit, cl, statsC);
}

__global__ void qgrad_kernel(const bf16* __restrict__ SG, const bf16* __restrict__ clb,
                             const int* __restrict__ csr, const int* __restrict__ offs,
                             const float* __restrict__ vdw, bf16* __restrict__ QG) {
  int t = blockIdx.x * 256 + threadIdx.x;
  int v = t >> 3, j = t & 7;
  if (v >= V_N) return;
  float gp[8], gn[8];
#pragma unroll
  for (int e = 0; e < 8; e++) { gp[e] = 0.0f; gn[e] = 0.0f; }
  int p0 = offs[v], p1 = offs[v + 1];
  for (int p = p0; p < p1; p++) {
    short8 x = *(const short8*)&clb[(size_t)csr[p] * 64 + j * 8];
#pragma unroll
    for (int e = 0; e < 8; e++) gp[e] += sb2f(x[e]);
  }
  p0 = offs[v + V_N]; p1 = offs[v + V_N + 1];
  for (int p = p0; p < p1; p++) {
    short8 x = *(const short8*)&clb[(size_t)csr[p] * 64 + j * 8];
#pragma unroll
    for (int e = 0; e < 8; e++) gn[e] += sb2f(x[e]);
  }
  short8 sgn = *(const short8*)&SG[(size_t)v * 64 + j * 8];          // sigmoid(-q)
  short8 sgp = *(const short8*)&SG[(size_t)(v + V_N) * 64 + j * 8];  // sigmoid(q)
  float w = vdw[v];
  short8 r;
#pragma unroll
  for (int e = 0; e < 8; e++)
    r[e] = f2sb((-sb2f(sgp[e]) * gp[e] + sb2f(sgn[e]) * gn[e]) * w);
  *(short8*)&QG[(size_t)v * 64 + j * 8] = r;
}

__device__ inline void vlb_body(int bidx, const bf16* Dl, const int* csr,
                                const int* offs, const float* dw,
                                bf16* VLb, float* statsV) {
  if (bidx == 0) {
    for (int i = threadIdx.x; i < 4096; i += 256) statsV[i] = 0.0f;
  }
  int t = bidx * 256 + threadIdx.x;
  int l = t >> 3, j = t & 7;
  if (l >= L_N) return;
  float s[8];
#pragma unroll
  for (int e = 0; e < 8; e++) s[e] = 0.0f;
  int p0 = offs[l], p1 = offs[l + 1];
  for (int p = p0; p < p1; p++) {
    short8 x = *(const short8*)&Dl[(size_t)csr[p] * 64 + j * 8];
#pragma unroll
    for (int e = 0; e < 8; e++) s[e] += sb2f(x[e]);
  }
  float w = dw[l];
  size_t v = (l < V_N) ? (size_t)l : (size_t)(l - V_N);
  int col = (l < V_N) ? 0 : 64;
  short8 r;
#pragma unroll
  for (int e = 0; e < 8; e++) r[e] = f2sb(s[e] * w);
  *(short8*)&VLb[v * 128 + col + j * 8] = r;
}

// pn stats body (one-pass S1,S2); wave covers rows ifirst, ifirst+8, ...
template<typename TX>
__device__ inline void pn_stats_body(const TX* X, const int* gid, int n,
                                     float* S1, float* S2, int wave, int nw) {
  int chunk = (n + nw - 1) / nw;
  int i0 = wave * chunk;
  if (i0 >= n) return;
  int i1 = min(n, i0 + chunk);
  int lane = threadIdx.x & 63;
  int sub = lane >> 3, j = lane & 7;
  float a1[8], a2[8];
#pragma unroll
  for (int e = 0; e < 8; e++) { a1[e] = 0.0f; a2[e] = 0.0f; }
  int ifirst = i0 + sub;
  if (ifirst >= i1) return;
  int g = gid[ifirst];
  for (int i = ifirst; i < i1; i += 8) {
    int gi = gid[i];
    if (gi != g) {
#pragma unroll
      for (int e = 0; e < 8; e++) {
        atomicAdd(&S1[g * 64 + j * 8 + e], a1[e]);
        atomicAdd(&S2[g * 64 + j * 8 + e], a2[e]);
        a1[e] = 0.0f; a2[e] = 0.0f;
      }
      g = gi;
    }
    float x[8];
    load8(&X[(size_t)i * 64 + j * 8], x);
#pragma unroll
    for (int e = 0; e < 8; e++) { a1[e] += x[e]; a2[e] += x[e] * x[e]; }
  }
#pragma unroll
  for (int e = 0; e < 8; e++) {
    atomicAdd(&S1[g * 64 + j * 8 + e], a1[e]);
    atomicAdd(&S2[g * 64 + j * 8 + e], a2[e]);
  }
}

// pn apply body: state = (pairnorm(X)*0.25 + 0.1*state) * post
template<typename TX>
__device__ inline void pn_apply_body(int bidx, const TX* X, const int* gid, int n,
                                     const int* cnt, const float* S1, const float* S2,
                                     bf16* state, float post) {
  int t = bidx * 256 + threadIdx.x;
  int i = t >> 3, j = t & 7;
  if (i >= n) return;
  int g = gid[i];
  float c = fmaxf((float)cnt[g], 1.0f);
  float m[8], tv = 0.0f;
#pragma unroll
  for (int e = 0; e < 8; e++) {
    m[e] = S1[g * 64 + j * 8 + e] / c;
    tv += S2[g * 64 + j * 8 + e] / c - m[e] * m[e];
  }
#pragma unroll
  for (int o = 1; o < 8; o <<= 1) tv += __shfl_xor(tv, o);
  float var = fmaxf(tv, 0.0f) * (1.0f / 64.0f);
  float rs = rsqrtf(var + 1e-6f);
  float x[8];
  load8(&X[(size_t)i * 64 + j * 8], x);
  short8 st = *(const short8*)&state[(size_t)i * 64 + j * 8];
  short8 r;
#pragma unroll
  for (int e = 0; e < 8; e++) {
    float xn = (x[e] - m[e]) * rs;
    r[e] = f2sb((xn * 0.25f + 0.1f * sb2f(st[e])) * post);
  }
  *(short8*)&state[(size_t)i * 64 + j * 8] = r;
}

// Merged: [vlb_gather (VLBB blocks)] || [pn_stats_c on Dn (SB blocks x4 waves)]
__global__ void vlb_statsc_kernel(const bf16* __restrict__ Dl, const int* __restrict__ csr,
                                  const int* __restrict__ offs, const float* __restrict__ dw,
                                  bf16* __restrict__ VLb, float* __restrict__ statsV,
                                  const bf16* __restrict__ Dn, const int* __restrict__ cgid,
                                  float* __restrict__ S1c, float* __restrict__ S2c,
                                  int VLBB) {
  if (blockIdx.x < VLBB) {
    vlb_body(blockIdx.x, Dl, csr, offs, dw, VLb, statsV);
  } else {
    int sb = blockIdx.x - VLBB;
    int wave = sb * 4 + (threadIdx.x >> 6);
    pn_stats_body<bf16>(Dn, cgid, C_N, S1c, S2c, wave, 512);
  }
}

// Merged: [pn_apply_c (AB blocks)] || [pn_stats_v on NV (SB blocks x4 waves)]
__global__ void applyc_statsv_kernel(const bf16* __restrict__ Dn, const int* __restrict__ cgid,
                                     const int* __restrict__ cntc, const float* __restrict__ S1c,
                                     const float* __restrict__ S2c, bf16* __restrict__ clauses,
                                     float post,
                                     const float* __restrict__ NV, const int* __restrict__ vgid,
                                     float* __restrict__ S1v, float* __restrict__ S2v,
                                     int AB) {
  if (blockIdx.x < AB) {
    pn_apply_body<bf16>(blockIdx.x, Dn, cgid, C_N, cntc, S1c, S2c, clauses, post);
  } else {
    int sb = blockIdx.x - AB;
    int wave = sb * 4 + (threadIdx.x >> 6);
    pn_stats_body<float>(NV, vgid, V_N, S1v, S2v, wave, 512);
  }
}

__global__ void pn_apply_v_kernel(const float* __restrict__ NV, const int* __restrict__ vgid,
                                  const int* __restrict__ cntv, const float* __restrict__ S1v,
                                  const float* __restrict__ S2v, bf16* __restrict__ variables) {
  pn_apply_body<float>(blockIdx.x, NV, vgid, V_N, cntv, S1v, S2v, variables, 1.0f);
}

// MFMA co MLP + noise + sigmoid. 64 rows/block; col-reduce via 16-lane shfl.
__global__ __launch_bounds__(256) void co_final_kernel(
    const bf16* __restrict__ clauses, const bf16* __restrict__ W0p,
    const void* __restrict__ b0, const void* __restrict__ W1,
    const void* __restrict__ b1, const int* __restrict__ flagp,
    uint32_t ka, uint32_t kb, float* __restrict__ out) {
  int tid = threadIdx.x;
  int wave = tid >> 6, lane = tid & 63, quad = lane >> 4, m16 = lane & 15;
  int row = blockIdx.x * 64 + wave * 16 + m16;
  int rowc = min(row, C_N - 1);
  int isf32 = *flagp;
  float4v acc[4];
#pragma unroll
  for (int nt = 0; nt < 4; nt++) acc[nt] = (float4v){0.f, 0.f, 0.f, 0.f};
  const short8* w0 = (const short8*)W0p;
  for (int k0 = 0; k0 < 64; k0 += 32) {
    short8 a = *(const short8*)&clauses[(size_t)rowc * 64 + k0 + quad * 8];
#pragma unroll
    for (int nt = 0; nt < 4; nt++) {
      short8 b = w0[((k0 >> 5) * 4 + nt) * 64 + lane];
      acc[nt] = __builtin_amdgcn_mfma_f32_16x16x32_bf16(a, b, acc[nt], 0, 0, 0);
    }
  }
  float s[4] = {0.f, 0.f, 0.f, 0.f};
#pragma unroll
  for (int nt = 0; nt < 4; nt++) {
    int col = nt * 16 + m16;
    float bv = wload(b0, col, isf32);
    float w1v = wload(W1, col, isf32);
#pragma unroll
    for (int i = 0; i < 4; i++) s[i] += fmaxf(acc[nt][i] + bv, 0.0f) * w1v;
  }
#pragma unroll
  for (int o = 1; o < 16; o <<= 1) {
#pragma unroll
    for (int i = 0; i < 4; i++) s[i] += __shfl_xor(s[i], o);
  }
  if (m16 == 0) {
    int rbase = blockIdx.x * 64 + wave * 16 + quad * 4;
    float bb = wload(b1, 0, isf32);
#pragma unroll
    for (int i = 0; i < 4; i++) {
      int r = rbase + i;
      if (r < C_N) {
        float lg = s[i] + bb + normal_from_bits(part_bits(ka, kb, (uint32_t)r));
        out[r] = 1.0f / (1.0f + expf(-lg));
      }
    }
  }
}

// ---------------------------------------------------------------------------
// Launch
// ---------------------------------------------------------------------------
extern "C" void kernel_launch(void* const* d_in, const int* in_sizes, int n_in,
                              void* d_out, int out_size, void* d_ws, size_t ws_size,
                              hipStream_t stream) {
  (void)in_sizes; (void)n_in; (void)out_size;
  const int* lit_idx    = (const int*)d_in[0];
  const int* var_gid    = (const int*)d_in[2];
  const int* clause_gid = (const int*)d_in[3];
  const void* vq_W0 = d_in[4];
  const void* vq_b0 = d_in[5];
  const void* vq_W1 = d_in[6];
  const void* vq_b1 = d_in[7];
  const void* cm_W0 = d_in[8];
  const void* cm_b0 = d_in[9];
  const void* cm_W1 = d_in[10];
  const void* cm_b1 = d_in[11];
  const void* ug_W0 = d_in[12];
  const void* ug_b0 = d_in[13];
  const void* ug_W1 = d_in[14];
  const void* ug_b1 = d_in[15];
  const void* ug_W2 = d_in[16];
  const void* ug_b2 = d_in[17];
  const void* co_W0 = d_in[18];
  const void* co_b0 = d_in[19];
  const void* co_W1 = d_in[20];
  const void* co_b1 = d_in[21];
  float* out = (float*)d_out;

  // ---- workspace layout (~226 MB peak; <= proven 233 MB) ----
  char* ws = (char*)d_ws;
  size_t off = 0;
  auto alloc = [&](size_t bytes) -> void* {
    void* p = ws + off;
    off = (off + bytes + 255) & ~(size_t)255;
    return p;
  };
  bf16* variables = (bf16*)alloc((size_t)V_N * 64 * 2);   // persistent state
  bf16* clauses   = (bf16*)alloc((size_t)C_N * 64 * 2);   // persistent state
  // ZE (C*64*2): clb -> Dn (in-place overlay in cm_fused)
  char* ZE        = (char*)alloc((size_t)C_N * 64 * 2);
  // ZD (C*64*2): Dl -> NV f32 (V*64)
  char* ZD        = (char*)alloc((size_t)C_N * 64 * 2);
  // ZS (L*64*2): SG (rounds launches 1-3) -> VLb (V*128, launches 5-6)
  char* ZS        = (char*)alloc((size_t)L_N * 64 * 2);
  bf16* QG        = (bf16*)alloc((size_t)V_N * 64 * 2);
  int*  izone     = (int*)alloc((size_t)(2 * L_N + 64) * 4);
  int*  offs      = (int*)alloc((size_t)(L_N + 1) * 4);
  int*  csr       = (int*)alloc((size_t)E_N * 4);
  int*  spart     = (int*)alloc((size_t)(2 * SCAN_NB + 2) * 4);
  float* deg_f    = (float*)alloc((size_t)L_N * 4);
  float* vdw      = (float*)alloc((size_t)V_N * 4);
  float* stats    = (float*)alloc((size_t)8192 * 4);
  int*   wflag    = (int*)alloc(256);
  // packed MFMA weights (bf16)
  bf16* vq_W0p = (bf16*)alloc((size_t)96 * 64 * 2);
  bf16* vq_W1p = (bf16*)alloc((size_t)64 * 64 * 2);
  bf16* cm_W0p = (bf16*)alloc((size_t)128 * 128 * 2);
  bf16* cm_W1p = (bf16*)alloc((size_t)128 * 128 * 2);
  bf16* ug_W0p = (bf16*)alloc((size_t)256 * 128 * 2);
  bf16* ug_W1p = (bf16*)alloc((size_t)128 * 128 * 2);
  bf16* ug_W2p = (bf16*)alloc((size_t)128 * 64 * 2);
  bf16* co_W0p = (bf16*)alloc((size_t)64 * 64 * 2);
  size_t need = off;

  auto nb = [](int n, int per) { return (n + per - 1) / per; };

  if (ws_size < need) {
    fill_f32<<<nb(C_N, 256), 256, 0, stream>>>(out, (size_t)C_N, 0.5f);
    return;
  }

  bf16* clb = (bf16*)ZE;                 // C x 64
  bf16* Dn  = (bf16*)ZE;                 // C x 64 (in-place overlay)
  bf16* Dl  = (bf16*)ZD;                 // C x 64
  float* NV = (float*)ZD;                // V x 64 f32 (after Dl consumed)
  bf16* SG  = (bf16*)ZS;                 // L x 64 sigmoid table
  bf16* VLb = (bf16*)ZS;                 // V x 128 (after SG dead)

  int* deg_i  = izone;
  int* cursor = izone + L_N;
  int* cntv   = izone + 2 * L_N;
  int* cntc   = cntv + 32;
  int* sbase  = spart + SCAN_NB;         // SCAN_NB+1 entries
  float* S1c = stats;              // 32 x 64
  float* S2c = stats + 2048;
  float* S1v = stats + 4096;
  float* S2v = stats + 6144;
  float* statsC = S1c;             // 4096 floats (S1c+S2c)
  float* statsV = S1v;             // 4096 floats (S1v+S2v)

  // JAX keys = split(key(42), 9), partitionable: subkey_i = threefry(key,0,i)
  uint32_t kw0[9], kw1[9];
  for (int i = 0; i < 9; i++) tf2x32(0u, 42u, 0u, (uint32_t)i, &kw0[i], &kw1[i]);

  const int BIG = 1 << 30;
  const int VLBB = nb(L_N * 8, 256);   // 6250 vlb blocks
  const int AB   = nb(C_N * 8, 256);   // 13125 apply_c blocks
  const int SB   = 128;                // pn_stats blocks (x4 waves = 512)

  // ---- setup (re-done every call) ----
  detect_dtype_kernel<<<1, 64, 0, stream>>>((const uint32_t*)vq_W0, wflag);
  fill_u32<<<nb(2 * L_N + 64, 256), 256, 0, stream>>>((uint32_t*)izone, (size_t)(2 * L_N + 64), 0u);
  count_deg_kernel<<<nb(E_N, 256), 256, 0, stream>>>(lit_idx, deg_i);
  hist32_kernel<<<nb(V_N, 256), 256, 0, stream>>>(var_gid, V_N, cntv);
  hist32_kernel<<<nb(C_N, 256), 256, 0, stream>>>(clause_gid, C_N, cntc);
  weights_kernel<<<nb(L_N, 256), 256, 0, stream>>>(deg_i, deg_f, vdw);
  scan_partial_kernel<<<SCAN_NB, 256, 0, stream>>>(deg_i, spart);
  scan_base_kernel<<<1, 256, 0, stream>>>(spart, sbase);
  scan_write_kernel<<<SCAN_NB, 256, 0, stream>>>(deg_i, sbase, offs);
  csr_fill_kernel<<<nb(E_N, 256), 256, 0, stream>>>(lit_idx, offs, cursor, csr);
  fill_b16<<<2048, 256, 0, stream>>>(variables, (size_t)V_N * 64, 1.0f);
  fill_b16<<<2048, 256, 0, stream>>>(clauses, (size_t)C_N * 64, 1.0f);
  // pack weights into MFMA B-fragment order
  pack_w_kernel<<<nb(96 * 64, 256), 256, 0, stream>>>(vq_W0, wflag, 68, 96, 64, 64, 0, BIG, 1.f, vq_W0p);
  pack_w_kernel<<<nb(64 * 64, 256), 256, 0, stream>>>(vq_W1, wflag, 64, 64, 64, 64, 0, BIG, 1.f, vq_W1p);
  pack_w_kernel<<<nb(128 * 128, 256), 256, 0, stream>>>(cm_W0, wflag, 128, 128, 128, 128, 0, 64, 4.f, cm_W0p);
  pack_w_kernel<<<nb(128 * 128, 256), 256, 0, stream>>>(cm_W1, wflag, 128, 128, 128, 128, 0, BIG, 1.f, cm_W1p);
  pack_w_kernel<<<nb(256 * 128, 256), 256, 0, stream>>>(ug_W0, wflag, 256, 256, 128, 128, 0, BIG, 1.f, ug_W0p);
  pack_w_kernel<<<nb(128 * 128, 256), 256, 0, stream>>>(ug_W1, wflag, 128, 128, 128, 128, 0, BIG, 1.f, ug_W1p);
  pack_w_kernel<<<nb(128 * 64, 256), 256, 0, stream>>>(ug_W2, wflag, 128, 128, 64, 64, 0, BIG, 1.f, ug_W2p);
  pack_w_kernel<<<nb(64 * 64, 256), 256, 0, stream>>>(co_W0, wflag, 64, 64, 64, 64, 0, BIG, 1.f, co_W0p);

  // ---- rounds (8 launches each) ----
  for (int r = 0; r < NROUNDS; r++) {
    vq_fused_kernel<<<nb(V_N, 64), 256, 0, stream>>>(
        variables, vq_W0p, vq_b0, vq_W1p, vq_b1, wflag, kw0[r], kw1[r], SG, V_N);
    cl_kernel<<<nb(C_N * 8, 256), 256, 0, stream>>>(SG, lit_idx, clb, statsC);
    qgrad_kernel<<<nb(V_N * 8, 256), 256, 0, stream>>>(SG, clb, csr, offs, vdw, QG);
    cm_fused_kernel<<<nb(C_N, 64), 256, 0, stream>>>(
        clauses, clb, cm_W0p, cm_b0, cm_W1p, cm_b1, wflag, Dl, Dn, C_N);
    // [vlb_gather (zeros statsV) || pn_stats_c]  — SG dead, VLb disjoint from Dl/Dn
    vlb_statsc_kernel<<<VLBB + SB, 256, 0, stream>>>(
        Dl, csr, offs, deg_f, VLb, statsV, Dn, clause_gid, S1c, S2c, VLBB);
    ug_fused_kernel<<<nb(V_N, 64), 256, 0, stream>>>(
        QG, variables, VLb, ug_W0p, ug_b0, ug_W1p, ug_b1, ug_W2p, ug_b2,
        wflag, NV, V_N);
    // [pn_apply_c || pn_stats_v]
    applyc_statsv_kernel<<<AB + SB, 256, 0, stream>>>(
        Dn, clause_gid, cntc, S1c, S2c, clauses, (r == NROUNDS - 1) ? 1.0f : 0.2f,
        NV, var_gid, S1v, S2v, AB);
    pn_apply_v_kernel<<<nb(V_N * 8, 256), 256, 0, stream>>>(
        NV, var_gid, cntv, S1v, S2v, variables);
  }
  co_final_kernel<<<nb(C_N, 64), 256, 0, stream>>>(
      clauses, co_W0p, co_b0, co_W1, co_b1, wflag, kw0[8], kw1[8], out);
}